// Round 9
// baseline (2814.880 us; speedup 1.0000x reference)
//
#include <hip/hip_runtime.h>

#define NTH  256
#define ROWS 32
#define F32LD 132   // padded f32 LDS row stride

enum { SF0 = 0, SF1, SO0, SO1, SO2, SO3, SM00, SM01, SM11, SP0, SP1,
       SDP0, SDP1, SV0, SV1, SV2, SM_N };

__device__ __forceinline__ float tanh_fast(float x) {
    float e = __expf(2.0f * x);
    return 1.0f - 2.0f / (e + 1.0f);
}
__device__ __forceinline__ float red8(float v) {
    v += __shfl_xor(v, 1);
    v += __shfl_xor(v, 2);
    v += __shfl_xor(v, 4);
    return v;
}

// acc[c] = sum_k Arow[k] * W[k*128 + vj0+c]   (forward: original row-major W)
__device__ __forceinline__ void mv_fwd(const float* __restrict__ W, const float* Arow,
                                       int vj0, float acc[16]) {
#pragma unroll
    for (int j = 0; j < 16; ++j) acc[j] = 0.f;
    for (int k = 0; k < 128; k += 4) {
        float4 a4 = *(const float4*)(Arow + k);
#pragma unroll
        for (int s = 0; s < 4; ++s) {
            float a = (s == 0) ? a4.x : (s == 1) ? a4.y : (s == 2) ? a4.z : a4.w;
            const float4* wp = (const float4*)(W + (size_t)(k + s) * 128 + vj0);
            float4 w0 = wp[0], w1 = wp[1], w2 = wp[2], w3 = wp[3];
            acc[0]  += a * w0.x; acc[1]  += a * w0.y; acc[2]  += a * w0.z; acc[3]  += a * w0.w;
            acc[4]  += a * w1.x; acc[5]  += a * w1.y; acc[6]  += a * w1.z; acc[7]  += a * w1.w;
            acc[8]  += a * w2.x; acc[9]  += a * w2.y; acc[10] += a * w2.z; acc[11] += a * w2.w;
            acc[12] += a * w3.x; acc[13] += a * w3.y; acc[14] += a * w3.z; acc[15] += a * w3.w;
        }
    }
}

// acc[c] = sum_k Trow[k] * W[(vj0+c)*128 + k]   (backward: row-of-W dot, contiguous k)
__device__ __forceinline__ void mv_bwd(const float* __restrict__ W, const float* Trow,
                                       int vj0, float acc[16]) {
#pragma unroll
    for (int j = 0; j < 16; ++j) acc[j] = 0.f;
    for (int k = 0; k < 128; k += 4) {
        float4 t4 = *(const float4*)(Trow + k);
#pragma unroll
        for (int c = 0; c < 16; ++c) {
            float4 w = *(const float4*)(W + (size_t)(vj0 + c) * 128 + k);
            acc[c] += t4.x * w.x + t4.y * w.y + t4.z * w.z + t4.w * w.w;
        }
    }
}

__global__ __launch_bounds__(NTH, 3)
void symoden_valu(const float* __restrict__ y,
                  const float* __restrict__ hW1, const float* __restrict__ hb1,
                  const float* __restrict__ hW2, const float* __restrict__ hb2,
                  const float* __restrict__ hW3,
                  const float* __restrict__ mW1, const float* __restrict__ mb1,
                  const float* __restrict__ mW2, const float* __restrict__ mb2,
                  const float* __restrict__ mW3, const float* __restrict__ mb3,
                  const float* __restrict__ gW1, const float* __restrict__ gb1,
                  const float* __restrict__ gW2, const float* __restrict__ gb2,
                  const float* __restrict__ gW3, const float* __restrict__ gb3,
                  float* __restrict__ out) {
    __shared__ __align__(16) float A0[ROWS * F32LD];   // g-h1 -> m-h1 -> h-h1
    __shared__ __align__(16) float A1[ROWS * F32LD];   // t -> u1
    __shared__ __align__(16) float FA[ROWS * F32LD];   // g-h2 -> m-h2 -> r -> u2
    __shared__ float iobuf[ROWS * 6];                  // y tile, then out tile
    __shared__ float sm[ROWS][SM_N];

    const int tid = threadIdx.x;
    const int vr  = tid >> 3;            // row within tile (8 threads/row)
    const int vj0 = (tid & 7) * 16;      // 16 cols per thread
    const size_t rowbase = (size_t)blockIdx.x * ROWS;

    if (tid < ROWS * 6) iobuf[tid] = y[rowbase * 6 + tid];
    __syncthreads();

    const float q0 = iobuf[vr * 6 + 0];
    const float q1 = iobuf[vr * 6 + 1];
    const float q2 = iobuf[vr * 6 + 2];
    float* Arow0 = &A0[vr * F32LD];
    float* Arow1 = &A1[vr * F32LD];
    float* FArow = &FA[vr * F32LD];

    // f32 factor registers (same-thread producer->consumer, static idx)
    float c1f[16];    // 1 - h1m^2  (P3 -> P10)
    float c2f[16];    // 1 - h2m^2  (P4 -> P11)
    float ch1f[16];   // 1 - h1h^2  (P6 -> P9)

    // ---- P1: g-L1 (K=3) -> A0 ----
#pragma unroll
    for (int c4 = 0; c4 < 16; c4 += 4) {
        int col = vj0 + c4;
        float4 w0 = *(const float4*)(gW1 + col);
        float4 w1 = *(const float4*)(gW1 + 128 + col);
        float4 w2 = *(const float4*)(gW1 + 256 + col);
        float4 bb = *(const float4*)(gb1 + col);
        float4 o;
        o.x = tanh_fast(bb.x + q0 * w0.x + q1 * w1.x + q2 * w2.x);
        o.y = tanh_fast(bb.y + q0 * w0.y + q1 * w1.y + q2 * w2.y);
        o.z = tanh_fast(bb.z + q0 * w0.z + q1 * w1.z + q2 * w2.z);
        o.w = tanh_fast(bb.w + q0 * w0.w + q1 * w1.w + q2 * w2.w);
        *(float4*)&A0[vr * F32LD + col] = o;
    }
    __syncthreads();

    // ---- P2: g-GEMM (VALU): A0 x gW2 -> tanh -> FA ----
    {
        float acc[16];
        mv_fwd(gW2, Arow0, vj0, acc);
#pragma unroll
        for (int c = 0; c < 16; ++c)
            FArow[vj0 + c] = tanh_fast(acc[c] + gb2[vj0 + c]);
    }
    __syncthreads();

    // ---- P3: g-L3 (N=2) -> F ; m-L1 -> A0 (+c1f) ----
    {
        float c0 = 0.f, c1 = 0.f;
#pragma unroll
        for (int c4 = 0; c4 < 16; c4 += 4) {
            float4 hv = *(const float4*)&FArow[vj0 + c4];
#pragma unroll
            for (int jj = 0; jj < 4; ++jj) {
                int col = vj0 + c4 + jj;
                float v = (jj == 0) ? hv.x : (jj == 1) ? hv.y : (jj == 2) ? hv.z : hv.w;
                float2 w = *(const float2*)(gW3 + col * 2);
                c0 += v * w.x;
                c1 += v * w.y;
            }
        }
        c0 = red8(c0);
        c1 = red8(c1);
        if ((tid & 7) == 0) {
            float uu = iobuf[vr * 6 + 5];
            sm[vr][SF0] = (c0 + gb3[0]) * uu;
            sm[vr][SF1] = (c1 + gb3[1]) * uu;
        }
#pragma unroll
        for (int c4 = 0; c4 < 16; c4 += 4) {
            int col = vj0 + c4;
            float4 w0 = *(const float4*)(mW1 + col);
            float4 w1 = *(const float4*)(mW1 + 128 + col);
            float4 w2 = *(const float4*)(mW1 + 256 + col);
            float4 bb = *(const float4*)(mb1 + col);
            float t0 = tanh_fast(bb.x + q0 * w0.x + q1 * w1.x + q2 * w2.x);
            float t1 = tanh_fast(bb.y + q0 * w0.y + q1 * w1.y + q2 * w2.y);
            float t2 = tanh_fast(bb.z + q0 * w0.z + q1 * w1.z + q2 * w2.z);
            float t3 = tanh_fast(bb.w + q0 * w0.w + q1 * w1.w + q2 * w2.w);
            c1f[c4 + 0] = 1.f - t0 * t0;
            c1f[c4 + 1] = 1.f - t1 * t1;
            c1f[c4 + 2] = 1.f - t2 * t2;
            c1f[c4 + 3] = 1.f - t3 * t3;
            *(float4*)&A0[vr * F32LD + col] = (float4){t0, t1, t2, t3};
        }
    }
    __syncthreads();

    // ---- P4: m-GEMM (VALU): A0 x mW2 -> tanh -> FA (+c2f) ----
    {
        float acc[16];
        mv_fwd(mW2, Arow0, vj0, acc);
#pragma unroll
        for (int c = 0; c < 16; ++c) {
            float th = tanh_fast(acc[c] + mb2[vj0 + c]);
            FArow[vj0 + c] = th;
            c2f[c] = 1.f - th * th;
        }
    }
    __syncthreads();

    // ---- P5: m-L3 (N=4) -> o, M, p ----
    {
        float c[4] = {0.f, 0.f, 0.f, 0.f};
#pragma unroll
        for (int c4 = 0; c4 < 16; c4 += 4) {
            float4 hv = *(const float4*)&FArow[vj0 + c4];
#pragma unroll
            for (int jj = 0; jj < 4; ++jj) {
                int col = vj0 + c4 + jj;
                float v = (jj == 0) ? hv.x : (jj == 1) ? hv.y : (jj == 2) ? hv.z : hv.w;
                float4 w = *(const float4*)(mW3 + col * 4);
                c[0] += v * w.x; c[1] += v * w.y; c[2] += v * w.z; c[3] += v * w.w;
            }
        }
#pragma unroll
        for (int cc = 0; cc < 4; ++cc) c[cc] = red8(c[cc]);
        if ((tid & 7) == 0) {
            float o0 = c[0] + mb3[0], o1 = c[1] + mb3[1];
            float o2 = c[2] + mb3[2], o3 = c[3] + mb3[3];
            float M00 = 1.f + o0 * o0 + o1 * o1;
            float M01 = o0 * o2 + o1 * o3;
            float M11 = 1.f + o2 * o2 + o3 * o3;
            float inv = 1.f / (M00 * M11 - M01 * M01);
            float x0 = iobuf[vr * 6 + 3], x1 = iobuf[vr * 6 + 4];
            sm[vr][SO0] = o0; sm[vr][SO1] = o1; sm[vr][SO2] = o2; sm[vr][SO3] = o3;
            sm[vr][SM00] = M00; sm[vr][SM01] = M01; sm[vr][SM11] = M11;
            sm[vr][SP0] = (M11 * x0 - M01 * x1) * inv;
            sm[vr][SP1] = (M00 * x1 - M01 * x0) * inv;
        }
    }
    __syncthreads();

    // ---- P6: h-L1 (K=5) -> A0 (+ch1f) ----
    {
        float p0 = sm[vr][SP0], p1 = sm[vr][SP1];
#pragma unroll
        for (int c4 = 0; c4 < 16; c4 += 4) {
            int col = vj0 + c4;
            float4 w0 = *(const float4*)(hW1 + col);
            float4 w1 = *(const float4*)(hW1 + 128 + col);
            float4 w2 = *(const float4*)(hW1 + 256 + col);
            float4 w3 = *(const float4*)(hW1 + 384 + col);
            float4 w4 = *(const float4*)(hW1 + 512 + col);
            float4 bb = *(const float4*)(hb1 + col);
            float t0 = tanh_fast(bb.x + q0 * w0.x + q1 * w1.x + q2 * w2.x + p0 * w3.x + p1 * w4.x);
            float t1 = tanh_fast(bb.y + q0 * w0.y + q1 * w1.y + q2 * w2.y + p0 * w3.y + p1 * w4.y);
            float t2 = tanh_fast(bb.z + q0 * w0.z + q1 * w1.z + q2 * w2.z + p0 * w3.z + p1 * w4.z);
            float t3 = tanh_fast(bb.w + q0 * w0.w + q1 * w1.w + q2 * w2.w + p0 * w3.w + p1 * w4.w);
            ch1f[c4 + 0] = 1.f - t0 * t0;
            ch1f[c4 + 1] = 1.f - t1 * t1;
            ch1f[c4 + 2] = 1.f - t2 * t2;
            ch1f[c4 + 3] = 1.f - t3 * t3;
            *(float4*)&A0[vr * F32LD + col] = (float4){t0, t1, t2, t3};
        }
    }
    __syncthreads();

    // ---- P7: h-GEMM (VALU): A0 x hW2 -> t = (1-h2^2)*hW3 -> A1 ----
    {
        float acc[16];
        mv_fwd(hW2, Arow0, vj0, acc);
#pragma unroll
        for (int c = 0; c < 16; ++c) {
            float th = tanh_fast(acc[c] + hb2[vj0 + c]);
            Arow1[vj0 + c] = (1.f - th * th) * hW3[vj0 + c];
        }
    }
    __syncthreads();

    // ---- P8: bwd-GEMM (VALU): r[i] = sum_k t[k]*hW2[i][k] -> FA ----
    {
        float acc[16];
        mv_bwd(hW2, Arow1, vj0, acc);
#pragma unroll
        for (int c = 0; c < 16; ++c)
            FArow[vj0 + c] = acc[c];
    }
    __syncthreads();

    // ---- P9: dH = (r .* ch1f) @ hW1^T (N=5); glue ----
    {
        float d0 = 0.f, d1 = 0.f, d2 = 0.f, d3 = 0.f, d4 = 0.f;
#pragma unroll
        for (int c4 = 0; c4 < 16; c4 += 4) {
            float4 rv = *(const float4*)&FArow[vj0 + c4];
#pragma unroll
            for (int jj = 0; jj < 4; ++jj) {
                int col = vj0 + c4 + jj;
                float r = (jj == 0) ? rv.x : (jj == 1) ? rv.y : (jj == 2) ? rv.z : rv.w;
                float s = r * ch1f[c4 + jj];
                d0 += s * hW1[col];
                d1 += s * hW1[128 + col];
                d2 += s * hW1[256 + col];
                d3 += s * hW1[384 + col];
                d4 += s * hW1[512 + col];
            }
        }
        d0 = red8(d0); d1 = red8(d1); d2 = red8(d2); d3 = red8(d3); d4 = red8(d4);
        if ((tid & 7) == 0) {
            float dHdq = -q2 * d1 + q1 * d2;
            float v0 = d3, v1 = -q2 * d4, v2 = q1 * d4;
            sm[vr][SDP0] = -d0 + sm[vr][SF0];
            sm[vr][SDP1] = -dHdq + sm[vr][SF1];
            sm[vr][SV0] = v0; sm[vr][SV1] = v1; sm[vr][SV2] = v2;
            iobuf[vr * 6 + 0] = v0;
            iobuf[vr * 6 + 1] = v1;
            iobuf[vr * 6 + 2] = v2;
        }
    }
    __syncthreads();

    // ---- P10: JVP u1 = (v @ mW1) .* c1f -> A1 ----
    {
        float v0 = sm[vr][SV0], v1 = sm[vr][SV1], v2 = sm[vr][SV2];
#pragma unroll
        for (int c4 = 0; c4 < 16; c4 += 4) {
            int col = vj0 + c4;
            float4 w0 = *(const float4*)(mW1 + col);
            float4 w1 = *(const float4*)(mW1 + 128 + col);
            float4 w2 = *(const float4*)(mW1 + 256 + col);
            float4 o;
            o.x = (v0 * w0.x + v1 * w1.x + v2 * w2.x) * c1f[c4 + 0];
            o.y = (v0 * w0.y + v1 * w1.y + v2 * w2.y) * c1f[c4 + 1];
            o.z = (v0 * w0.z + v1 * w1.z + v2 * w2.z) * c1f[c4 + 2];
            o.w = (v0 * w0.w + v1 * w1.w + v2 * w2.w) * c1f[c4 + 3];
            *(float4*)&A1[vr * F32LD + col] = o;
        }
    }
    __syncthreads();

    // ---- P11: JVP-GEMM (VALU): A1(u1) x mW2 -> u2 = .* c2f -> FA ----
    {
        float acc[16];
        mv_fwd(mW2, Arow1, vj0, acc);
#pragma unroll
        for (int c = 0; c < 16; ++c)
            FArow[vj0 + c] = acc[c] * c2f[c];
    }
    __syncthreads();

    // ---- P12: do = u2 @ mW3 (N=4); final glue ----
    {
        float c[4] = {0.f, 0.f, 0.f, 0.f};
#pragma unroll
        for (int c4 = 0; c4 < 16; c4 += 4) {
            float4 uv = *(const float4*)&FArow[vj0 + c4];
#pragma unroll
            for (int jj = 0; jj < 4; ++jj) {
                int col = vj0 + c4 + jj;
                float u = (jj == 0) ? uv.x : (jj == 1) ? uv.y : (jj == 2) ? uv.z : uv.w;
                float4 w = *(const float4*)(mW3 + col * 4);
                c[0] += u * w.x; c[1] += u * w.y; c[2] += u * w.z; c[3] += u * w.w;
            }
        }
#pragma unroll
        for (int cc = 0; cc < 4; ++cc) c[cc] = red8(c[cc]);
        if ((tid & 7) == 0) {
            float o0 = sm[vr][SO0], o1 = sm[vr][SO1], o2 = sm[vr][SO2], o3 = sm[vr][SO3];
            float do0 = c[0], do1 = c[1], do2 = c[2], do3 = c[3];
            float dM00 = 2.f * (do0 * o0 + do1 * o1);
            float dM11 = 2.f * (do2 * o2 + do3 * o3);
            float dM01 = do0 * o2 + do1 * o3 + o0 * do2 + o1 * do3;
            float M00 = sm[vr][SM00], M01 = sm[vr][SM01], M11 = sm[vr][SM11];
            float p0 = sm[vr][SP0], p1 = sm[vr][SP1];
            float dp0 = sm[vr][SDP0], dp1 = sm[vr][SDP1];
            iobuf[vr * 6 + 3] = M00 * dp0 + M01 * dp1 + dM00 * p0 + dM01 * p1;
            iobuf[vr * 6 + 4] = M01 * dp0 + M11 * dp1 + dM01 * p0 + dM11 * p1;
            iobuf[vr * 6 + 5] = 0.f;
        }
    }
    __syncthreads();

    if (tid < ROWS * 6) out[rowbase * 6 + tid] = iobuf[tid];
}

extern "C" void kernel_launch(void* const* d_in, const int* in_sizes, int n_in,
                              void* d_out, int out_size, void* d_ws, size_t ws_size,
                              hipStream_t stream) {
    (void)n_in; (void)d_ws; (void)ws_size; (void)out_size;
    const float* y   = (const float*)d_in[1];
    const float* hW1 = (const float*)d_in[2];
    const float* hb1 = (const float*)d_in[3];
    const float* hW2 = (const float*)d_in[4];
    const float* hb2 = (const float*)d_in[5];
    const float* hW3 = (const float*)d_in[6];
    const float* mW1 = (const float*)d_in[8];
    const float* mb1 = (const float*)d_in[9];
    const float* mW2 = (const float*)d_in[10];
    const float* mb2 = (const float*)d_in[11];
    const float* mW3 = (const float*)d_in[12];
    const float* mb3 = (const float*)d_in[13];
    const float* gW1 = (const float*)d_in[14];
    const float* gb1 = (const float*)d_in[15];
    const float* gW2 = (const float*)d_in[16];
    const float* gb2 = (const float*)d_in[17];
    const float* gW3 = (const float*)d_in[18];
    const float* gb3 = (const float*)d_in[19];
    float* out = (float*)d_out;

    int nrows = in_sizes[1] / 6;              // 131072
    dim3 grid(nrows / ROWS), block(NTH);      // 4096 x 256
    symoden_valu<<<grid, block, 0, stream>>>(y, hW1, hb1, hW2, hb2, hW3,
                                             mW1, mb1, mW2, mb2, mW3, mb3,
                                             gW1, gb1, gW2, gb2, gW3, gb3, out);
}